// Round 8
// baseline (171.943 us; speedup 1.0000x reference)
//
#include <hip/hip_runtime.h>
#include <stdint.h>
#include <math.h>

#define NB 4
#define NN 1024
#define ND 64
#define RPH 36   // padded LDS row length (f32) for a 32-wide d-half tile

typedef float v2f __attribute__((ext_vector_type(2)));

__device__ __forceinline__ v2f pk_add(v2f a, v2f b) {
  v2f d;
  asm("v_pk_add_f32 %0, %1, %2" : "=v"(d) : "v"(a), "v"(b));
  return d;
}
__device__ __forceinline__ v2f pk_fma(v2f a, v2f b, v2f c) {
  v2f d;
  asm("v_pk_fma_f32 %0, %1, %2, %3" : "=v"(d) : "v"(a), "v"(b), "v"(c));
  return d;
}

// Static device scratch: f64 (exact fallback) + f32 (fast path) h arrays
__device__ double g_hs64[NB * NN * ND];
__device__ double g_hd64[NB * NN * ND];
__device__ float  g_hs32[NB * NN * ND];
__device__ float  g_hd32[NB * NN * ND];
__device__ double g_w2d[ND];
__device__ float  g_w2f[ND];

// ---- Threefry-2x32-20 core ----
__device__ __forceinline__ void threefry_core(uint32_t K0, uint32_t K1,
                                              uint32_t x0, uint32_t x1,
                                              uint32_t& o0, uint32_t& o1) {
  const uint32_t K2 = K0 ^ K1 ^ 0x1BD11BDAu;
  x0 += K0; x1 += K1;
#define TF_RND(r) { x0 += x1; x1 = (x1 << r) | (x1 >> (32 - r)); x1 ^= x0; }
  TF_RND(13) TF_RND(15) TF_RND(26) TF_RND(6)
  x0 += K1; x1 += K2 + 1u;
  TF_RND(17) TF_RND(29) TF_RND(16) TF_RND(24)
  x0 += K2; x1 += K0 + 2u;
  TF_RND(13) TF_RND(15) TF_RND(26) TF_RND(6)
  x0 += K0; x1 += K1 + 3u;
  TF_RND(17) TF_RND(29) TF_RND(16) TF_RND(24)
  x0 += K1; x1 += K2 + 4u;
  TF_RND(13) TF_RND(15) TF_RND(26) TF_RND(6)
  x0 += K2; x1 += K0 + 5u;
#undef TF_RND
  o0 = x0; o1 = x1;
}

// jax_threefry_partitionable stream (verified r3): word(L) = o0^o1, x=(0,L)
__device__ __forceinline__ uint32_t rand_word(uint32_t L) {
  uint32_t o0, o1;
  threefry_core(0u, 42u, 0u, L, o0, o1);
  return o0 ^ o1;
}

// exact f32 uniform(tiny,1) — bit-identical to JAX
__device__ __forceinline__ float u_from_word(uint32_t w) {
  uint32_t fb = (w >> 9) | 0x3f800000u;
  float f = __uint_as_float(fb) - 1.0f;
  const float tinyf = 1.17549435e-38f;
  return fmaxf(tinyf, f + tinyf);
}

// ---- exact-f64 fallback for near-boundary cells (matches r3/r4 pipeline) ----
__device__ __attribute__((noinline)) float decide_fallback(int b, int i, int j,
                                                           uint32_t m, double b2d) {
  const double* hsi = g_hs64 + ((size_t)(b * NN + i)) * ND;
  const double* hdi = g_hd64 + ((size_t)(b * NN + i)) * ND;
  const double* hsj = g_hs64 + ((size_t)(b * NN + j)) * ND;
  const double* hdj = g_hd64 + ((size_t)(b * NN + j)) * ND;
  double l1 = 0.0, l2 = 0.0;
  for (int d = 0; d < ND; ++d) {
    double w = g_w2d[d];
    l1 += fmax(hsi[d] + hdj[d], 0.0) * w;
    l2 += fmax(hsj[d] + hdi[d], 0.0) * w;
  }
  double sym = 0.5 * (l1 + l2) + b2d;
  double E = exp(sym);
  double L0 = -log((double)u_from_word(rand_word(2u * m)));
  double L1 = -log((double)u_from_word(rand_word(2u * m + 1u)));
  return (E * L1 >= L0) ? 1.0f : 0.0f;
}

// ---- Stage 1: f64 h arrays + f32 copies + W2 broadcast ----
__global__ __launch_bounds__(256) void stage1(const float* __restrict__ nf,
                                              const float* __restrict__ W1,
                                              const float* __restrict__ b1,
                                              const float* __restrict__ W2) {
  __shared__ float w1s[2 * ND][ND];   // 32 KB
  __shared__ float rows[4][ND];
  const int tid = threadIdx.x;
  const float4* W14 = (const float4*)W1;
  float4* w1s4 = (float4*)w1s;
  #pragma unroll
  for (int p = 0; p < 8; ++p) w1s4[tid + 256 * p] = W14[tid + 256 * p];
  const int r = tid >> 6, e = tid & 63;
  const int bn = blockIdx.x * 4 + r;
  rows[r][e] = nf[bn * ND + e];
  __syncthreads();
  double accs = 0.0, accd = 0.0;
  #pragma unroll
  for (int k = 0; k < ND; ++k) {
    double x = (double)rows[r][k];
    accs = fma(x, (double)w1s[k][e], accs);
    accd = fma(x, (double)w1s[ND + k][e], accd);
  }
  accd += (double)b1[e];
  const int o = bn * ND + e;
  g_hs64[o] = accs;  g_hd64[o] = accd;
  g_hs32[o] = (float)accs;  g_hd32[o] = (float)accd;
  if (blockIdx.x == 0 && tid < ND) {
    g_w2d[tid] = (double)W2[tid];
    g_w2f[tid] = W2[tid];
  }
}

// ---- Stage 2: 32x32 pair tile, d-split LDS (19KB), packed-f32 main loop ----
__global__ __launch_bounds__(256, 8) void stage2(const float* __restrict__ b2,
                                                 float* __restrict__ adj,
                                                 float* __restrict__ logits) {
  const int t = blockIdx.x;
  const int b = t / 528;
  const int k = t - b * 528;
#define TRI_S(x) ((x) * 32 - ((x) * ((x) - 1)) / 2)
  int bi = (int)((65.0 - sqrt((double)(4225 - 8 * k))) * 0.5);
  while (k >= TRI_S(bi + 1)) ++bi;
  while (k < TRI_S(bi)) --bi;
  const int bj = bi + (k - TRI_S(bi));
#undef TRI_S
  const int i0 = bi * 32, j0 = bj * 32;

  // arrays: 0=si (i-rows of hs), 1=di (i-rows of hd), 2=sj, 3=dj
  __shared__ float sh[4][32][RPH];   // 18.4 KB
  __shared__ float w2s[ND];

  const int tid = threadIdx.x;
  const int tx = tid & 15, ty = tid >> 4;
  if (tid < ND) w2s[tid] = g_w2f[tid];

  v2f a1[2][2], a2[2][2];
  #pragma unroll
  for (int a = 0; a < 2; ++a)
    #pragma unroll
    for (int c = 0; c < 2; ++c) { a1[a][c] = (v2f)(0.f); a2[a][c] = (v2f)(0.f); }

  const int srow = tid >> 3;            // 0..31
  const int scol = (tid & 7) << 2;      // 0,4,..,28

  #pragma unroll
  for (int h = 0; h < 2; ++h) {
    if (h) __syncthreads();             // protect LDS overwrite
    const int d0 = h * 32;
    #pragma unroll
    for (int p = 0; p < 4; ++p) {
      const float* src = (p & 1) ? g_hd32 : g_hs32;
      const int base = (p < 2) ? i0 : j0;
      float4 v = *(const float4*)(src + ((size_t)(b * NN + base + srow)) * ND + d0 + scol);
      *(float4*)&sh[p][srow][scol] = v;
    }
    __syncthreads();

    #pragma unroll
    for (int dd = 0; dd < 32; dd += 4) {
      const float4 w4  = *(const float4*)&w2s[d0 + dd];
      const float4 si0 = *(const float4*)&sh[0][ty][dd];
      const float4 si1 = *(const float4*)&sh[0][ty + 16][dd];
      const float4 di0 = *(const float4*)&sh[1][ty][dd];
      const float4 di1 = *(const float4*)&sh[1][ty + 16][dd];
      const float4 sj0 = *(const float4*)&sh[2][tx][dd];
      const float4 sj1 = *(const float4*)&sh[2][tx + 16][dd];
      const float4 dj0 = *(const float4*)&sh[3][tx][dd];
      const float4 dj1 = *(const float4*)&sh[3][tx + 16][dd];

      #pragma unroll
      for (int k2 = 0; k2 < 2; ++k2) {
        v2f w_, si[2], di[2], sj[2], dj[2];
        if (k2 == 0) {
          w_ = (v2f){w4.x, w4.y};
          si[0] = (v2f){si0.x, si0.y}; si[1] = (v2f){si1.x, si1.y};
          di[0] = (v2f){di0.x, di0.y}; di[1] = (v2f){di1.x, di1.y};
          sj[0] = (v2f){sj0.x, sj0.y}; sj[1] = (v2f){sj1.x, sj1.y};
          dj[0] = (v2f){dj0.x, dj0.y}; dj[1] = (v2f){dj1.x, dj1.y};
        } else {
          w_ = (v2f){w4.z, w4.w};
          si[0] = (v2f){si0.z, si0.w}; si[1] = (v2f){si1.z, si1.w};
          di[0] = (v2f){di0.z, di0.w}; di[1] = (v2f){di1.z, di1.w};
          sj[0] = (v2f){sj0.z, sj0.w}; sj[1] = (v2f){sj1.z, sj1.w};
          dj[0] = (v2f){dj0.z, dj0.w}; dj[1] = (v2f){dj1.z, dj1.w};
        }
        #pragma unroll
        for (int a = 0; a < 2; ++a)
          #pragma unroll
          for (int c = 0; c < 2; ++c) {
            v2f t1 = pk_add(si[a], dj[c]);
            t1.x = fmaxf(t1.x, 0.f); t1.y = fmaxf(t1.y, 0.f);
            a1[a][c] = pk_fma(t1, w_, a1[a][c]);
            v2f t2 = pk_add(sj[c], di[a]);
            t2.x = fmaxf(t2.x, 0.f); t2.y = fmaxf(t2.y, 0.f);
            a2[a][c] = pk_fma(t2, w_, a2[a][c]);
          }
      }
    }
  }

  const float b2f = b2[0];
  const double b2d = (double)b2f;

  #pragma unroll
  for (int a = 0; a < 2; ++a)
    #pragma unroll
    for (int c = 0; c < 2; ++c) {
      const int i = i0 + ty + 16 * a;
      const int j = j0 + tx + 16 * c;
      const float l1 = a1[a][c].x + a1[a][c].y;
      const float l2 = a2[a][c].x + a2[a][c].y;
      const float symf = 0.5f * (l1 + l2) + b2f;
      const uint32_t m1 = (uint32_t)((b * NN + i) * NN + j);
      const uint32_t m2 = (uint32_t)((b * NN + j) * NN + i);

      const float E = __expf(symf);
      const float L0a = -__logf(u_from_word(rand_word(2u * m1)));
      const float L1a = -__logf(u_from_word(rand_word(2u * m1 + 1u)));
      const float L0b = -__logf(u_from_word(rand_word(2u * m2)));
      const float L1b = -__logf(u_from_word(rand_word(2u * m2 + 1u)));

      float adj1, adj2;
      if (i == j) {
        adj1 = 0.f; adj2 = 0.f;
      } else {
        const float pa = E * L1a, da = pa - L0a;
        const float pb = E * L1b, db = pb - L0b;
        const bool flagA = (fabsf(da) < 2e-3f * (pa + L0a)) || ((pa + L0a) < 2e-6f);
        const bool flagB = (fabsf(db) < 2e-3f * (pb + L0b)) || ((pb + L0b) < 2e-6f);
        adj1 = flagA ? decide_fallback(b, i, j, m1, b2d) : (da >= 0.f ? 1.f : 0.f);
        adj2 = flagB ? decide_fallback(b, i, j, m2, b2d) : (db >= 0.f ? 1.f : 0.f);
      }

      logits[m1] = symf;
      logits[m2] = symf;
      adj[m1] = adj1;
      adj[m2] = adj2;
    }
}

extern "C" void kernel_launch(void* const* d_in, const int* in_sizes, int n_in,
                              void* d_out, int out_size, void* d_ws, size_t ws_size,
                              hipStream_t stream) {
  const float* nf = (const float*)d_in[0];   // [4,1024,64]
  const float* W1 = (const float*)d_in[1];   // [128,64]
  const float* b1 = (const float*)d_in[2];   // [64]
  const float* W2 = (const float*)d_in[3];   // [64,1]
  const float* b2 = (const float*)d_in[4];   // [1]

  float* adj    = (float*)d_out;                       // [4,1024,1024]
  float* logits = adj + (size_t)NB * NN * NN;          // [4,1024,1024]

  stage1<<<dim3(NB * NN / 4), dim3(256), 0, stream>>>(nf, W1, b1, W2);
  stage2<<<dim3(NB * 528), dim3(256), 0, stream>>>(b2, adj, logits);
}

// Round 9
// 171.055 us; speedup vs baseline: 1.0052x; 1.0052x over previous
//
#include <hip/hip_runtime.h>
#include <stdint.h>
#include <math.h>

#define NB 4
#define NN 1024
#define ND 64
#define RPH 36   // padded LDS row stride (f32), 16B-aligned
#define TS 36    // write-staging tile row stride

// Static device scratch: f64 (exact fallback) + f32 (fast path) h arrays
__device__ double g_hs64[NB * NN * ND];
__device__ double g_hd64[NB * NN * ND];
__device__ float  g_hs32[NB * NN * ND];
__device__ float  g_hd32[NB * NN * ND];
__device__ double g_w2d[ND];
__device__ float  g_w2f[ND];

// ---- Threefry-2x32-20 core ----
__device__ __forceinline__ void threefry_core(uint32_t K0, uint32_t K1,
                                              uint32_t x0, uint32_t x1,
                                              uint32_t& o0, uint32_t& o1) {
  const uint32_t K2 = K0 ^ K1 ^ 0x1BD11BDAu;
  x0 += K0; x1 += K1;
#define TF_RND(r) { x0 += x1; x1 = (x1 << r) | (x1 >> (32 - r)); x1 ^= x0; }
  TF_RND(13) TF_RND(15) TF_RND(26) TF_RND(6)
  x0 += K1; x1 += K2 + 1u;
  TF_RND(17) TF_RND(29) TF_RND(16) TF_RND(24)
  x0 += K2; x1 += K0 + 2u;
  TF_RND(13) TF_RND(15) TF_RND(26) TF_RND(6)
  x0 += K0; x1 += K1 + 3u;
  TF_RND(17) TF_RND(29) TF_RND(16) TF_RND(24)
  x0 += K1; x1 += K2 + 4u;
  TF_RND(13) TF_RND(15) TF_RND(26) TF_RND(6)
  x0 += K2; x1 += K0 + 5u;
#undef TF_RND
  o0 = x0; o1 = x1;
}

// jax_threefry_partitionable stream (verified r3): word(L) = o0^o1, x=(0,L)
__device__ __forceinline__ uint32_t rand_word(uint32_t L) {
  uint32_t o0, o1;
  threefry_core(0u, 42u, 0u, L, o0, o1);
  return o0 ^ o1;
}

// exact f32 uniform(tiny,1) — bit-identical to JAX
__device__ __forceinline__ float u_from_word(uint32_t w) {
  uint32_t fb = (w >> 9) | 0x3f800000u;
  float f = __uint_as_float(fb) - 1.0f;
  const float tinyf = 1.17549435e-38f;
  return fmaxf(tinyf, f + tinyf);
}

// ---- exact-f64 fallback for near-boundary cells (matches r3/r4 pipeline) ----
__device__ __attribute__((noinline)) float decide_fallback(int b, int i, int j,
                                                           uint32_t m, double b2d) {
  const double* hsi = g_hs64 + ((size_t)(b * NN + i)) * ND;
  const double* hdi = g_hd64 + ((size_t)(b * NN + i)) * ND;
  const double* hsj = g_hs64 + ((size_t)(b * NN + j)) * ND;
  const double* hdj = g_hd64 + ((size_t)(b * NN + j)) * ND;
  double l1 = 0.0, l2 = 0.0;
  for (int d = 0; d < ND; ++d) {
    double w = g_w2d[d];
    l1 += fmax(hsi[d] + hdj[d], 0.0) * w;
    l2 += fmax(hsj[d] + hdi[d], 0.0) * w;
  }
  double sym = 0.5 * (l1 + l2) + b2d;
  double E = exp(sym);
  double L0 = -log((double)u_from_word(rand_word(2u * m)));
  double L1 = -log((double)u_from_word(rand_word(2u * m + 1u)));
  return (E * L1 >= L0) ? 1.0f : 0.0f;
}

// ---- Stage 1: f64 h arrays + f32 copies + W2 broadcast ----
__global__ __launch_bounds__(256) void stage1(const float* __restrict__ nf,
                                              const float* __restrict__ W1,
                                              const float* __restrict__ b1,
                                              const float* __restrict__ W2) {
  __shared__ float w1s[2 * ND][ND];   // 32 KB
  __shared__ float rows[4][ND];
  const int tid = threadIdx.x;
  const float4* W14 = (const float4*)W1;
  float4* w1s4 = (float4*)w1s;
  #pragma unroll
  for (int p = 0; p < 8; ++p) w1s4[tid + 256 * p] = W14[tid + 256 * p];
  const int r = tid >> 6, e = tid & 63;
  const int bn = blockIdx.x * 4 + r;
  rows[r][e] = nf[bn * ND + e];
  __syncthreads();
  double accs = 0.0, accd = 0.0;
  #pragma unroll
  for (int k = 0; k < ND; ++k) {
    double x = (double)rows[r][k];
    accs = fma(x, (double)w1s[k][e], accs);
    accd = fma(x, (double)w1s[ND + k][e], accd);
  }
  accd += (double)b1[e];
  const int o = bn * ND + e;
  g_hs64[o] = accs;  g_hd64[o] = accd;
  g_hs32[o] = (float)accs;  g_hd32[o] = (float)accd;
  if (blockIdx.x == 0 && tid < ND) {
    g_w2d[tid] = (double)W2[tid];
    g_w2f[tid] = W2[tid];
  }
}

// ---- Stage 2: 32x32 pair tile, d-split LDS, coalesced LDS-staged epilogue ----
__global__ __launch_bounds__(256, 8) void stage2(const float* __restrict__ b2,
                                                 float* __restrict__ adj,
                                                 float* __restrict__ logits) {
  const int t = blockIdx.x;
  const int b = t / 528;
  const int k = t - b * 528;
#define TRI_S(x) ((x) * 32 - ((x) * ((x) - 1)) / 2)
  int bi = (int)((65.0 - sqrt((double)(4225 - 8 * k))) * 0.5);
  while (k >= TRI_S(bi + 1)) ++bi;
  while (k < TRI_S(bi)) --bi;
  const int bj = bi + (k - TRI_S(bi));
#undef TRI_S
  const int i0 = bi * 32, j0 = bj * 32;

  // compute phase: sh = [4][32][RPH]; write phase: aliased as 3 staging tiles
  __shared__ float sh[4 * 32 * RPH];   // 18.4 KB
  __shared__ float w2s[ND];

  const int tid = threadIdx.x;
  const int tx = tid & 15, ty = tid >> 4;
  if (tid < ND) w2s[tid] = g_w2f[tid];

  float a1[2][2] = {{0.f, 0.f}, {0.f, 0.f}};
  float a2[2][2] = {{0.f, 0.f}, {0.f, 0.f}};

  const int srow = tid >> 3;            // 0..31
  const int scol = (tid & 7) << 2;      // 0,4,..,28

#define SH(p, r, c) sh[((p) * 32 + (r)) * RPH + (c)]

  #pragma unroll
  for (int h = 0; h < 2; ++h) {
    if (h) __syncthreads();             // protect LDS overwrite
    const int d0 = h * 32;
    #pragma unroll
    for (int p = 0; p < 4; ++p) {
      const float* src = (p & 1) ? g_hd32 : g_hs32;
      const int base = (p < 2) ? i0 : j0;
      float4 v = *(const float4*)(src + ((size_t)(b * NN + base + srow)) * ND + d0 + scol);
      *(float4*)&SH(p, srow, scol) = v;
    }
    __syncthreads();

    #pragma unroll
    for (int dd = 0; dd < 32; dd += 4) {
      const float4 w4  = *(const float4*)&w2s[d0 + dd];
      const float4 si0 = *(const float4*)&SH(0, ty, dd);
      const float4 si1 = *(const float4*)&SH(0, ty + 16, dd);
      const float4 di0 = *(const float4*)&SH(1, ty, dd);
      const float4 di1 = *(const float4*)&SH(1, ty + 16, dd);
      const float4 sj0 = *(const float4*)&SH(2, tx, dd);
      const float4 sj1 = *(const float4*)&SH(2, tx + 16, dd);
      const float4 dj0 = *(const float4*)&SH(3, tx, dd);
      const float4 dj1 = *(const float4*)&SH(3, tx + 16, dd);

      const float* wv = (const float*)&w4;
      const float* siA[2] = {(const float*)&si0, (const float*)&si1};
      const float* diA[2] = {(const float*)&di0, (const float*)&di1};
      const float* sjA[2] = {(const float*)&sj0, (const float*)&sj1};
      const float* djA[2] = {(const float*)&dj0, (const float*)&dj1};

      #pragma unroll
      for (int kk = 0; kk < 4; ++kk) {
        const float w = wv[kk];
        #pragma unroll
        for (int a = 0; a < 2; ++a)
          #pragma unroll
          for (int c = 0; c < 2; ++c) {
            a1[a][c] = fmaf(fmaxf(siA[a][kk] + djA[c][kk], 0.f), w, a1[a][c]);
            a2[a][c] = fmaf(fmaxf(sjA[c][kk] + diA[a][kk], 0.f), w, a2[a][c]);
          }
      }
    }
  }

  const float b2f = b2[0];
  const double b2d = (double)b2f;

  // ---- epilogue: decide + stage into LDS tiles (aliases sh) ----
  float* Lg = sh;              // [32][TS] logits, (i-row, j-col) orientation
  float* A1 = sh + 32 * TS;    // [32][TS] adj, (i-row, j-col)
  float* A2 = sh + 64 * TS;    // [32][TS] adj, (j-row, i-col)

  __syncthreads();             // all compute reads of sh complete

  #pragma unroll
  for (int a = 0; a < 2; ++a)
    #pragma unroll
    for (int c = 0; c < 2; ++c) {
      const int rr = ty + 16 * a;        // local i
      const int cc = tx + 16 * c;        // local j
      const int i = i0 + rr, j = j0 + cc;
      const float symf = 0.5f * (a1[a][c] + a2[a][c]) + b2f;
      const uint32_t m1 = (uint32_t)((b * NN + i) * NN + j);
      const uint32_t m2 = (uint32_t)((b * NN + j) * NN + i);

      float adj1, adj2;
      if (i == j) {
        adj1 = 0.f; adj2 = 0.f;
      } else {
        const float E = __expf(symf);
        const float L0a = -__logf(u_from_word(rand_word(2u * m1)));
        const float L1a = -__logf(u_from_word(rand_word(2u * m1 + 1u)));
        const float L0b = -__logf(u_from_word(rand_word(2u * m2)));
        const float L1b = -__logf(u_from_word(rand_word(2u * m2 + 1u)));
        const float pa = E * L1a, da = pa - L0a;
        const float pb = E * L1b, db = pb - L0b;
        const bool flagA = (fabsf(da) < 2e-3f * (pa + L0a)) || ((pa + L0a) < 2e-6f);
        const bool flagB = (fabsf(db) < 2e-3f * (pb + L0b)) || ((pb + L0b) < 2e-6f);
        adj1 = flagA ? decide_fallback(b, i, j, m1, b2d) : (da >= 0.f ? 1.f : 0.f);
        adj2 = flagB ? decide_fallback(b, i, j, m2, b2d) : (db >= 0.f ? 1.f : 0.f);
      }

      Lg[rr * TS + cc] = symf;
      A1[rr * TS + cc] = adj1;
      A2[cc * TS + rr] = adj2;
    }

  __syncthreads();

  // ---- coalesced writes: full float4 rows for all four regions ----
  {
    const int r = tid >> 3;             // 0..31
    const int c4 = (tid & 7) << 2;      // 0,4,..,28
    const size_t rowI = ((size_t)(b * NN + i0 + r)) * NN + j0 + c4;
    const size_t rowJ = ((size_t)(b * NN + j0 + r)) * NN + i0 + c4;

    *(float4*)&logits[rowI] = *(const float4*)&Lg[r * TS + c4];
    float4 lt;
    lt.x = Lg[(c4 + 0) * TS + r];
    lt.y = Lg[(c4 + 1) * TS + r];
    lt.z = Lg[(c4 + 2) * TS + r];
    lt.w = Lg[(c4 + 3) * TS + r];
    *(float4*)&logits[rowJ] = lt;
    *(float4*)&adj[rowI] = *(const float4*)&A1[r * TS + c4];
    *(float4*)&adj[rowJ] = *(const float4*)&A2[r * TS + c4];
  }
#undef SH
}

extern "C" void kernel_launch(void* const* d_in, const int* in_sizes, int n_in,
                              void* d_out, int out_size, void* d_ws, size_t ws_size,
                              hipStream_t stream) {
  const float* nf = (const float*)d_in[0];   // [4,1024,64]
  const float* W1 = (const float*)d_in[1];   // [128,64]
  const float* b1 = (const float*)d_in[2];   // [64]
  const float* W2 = (const float*)d_in[3];   // [64,1]
  const float* b2 = (const float*)d_in[4];   // [1]

  float* adj    = (float*)d_out;                       // [4,1024,1024]
  float* logits = adj + (size_t)NB * NN * NN;          // [4,1024,1024]

  stage1<<<dim3(NB * NN / 4), dim3(256), 0, stream>>>(nf, W1, b1, W2);
  stage2<<<dim3(NB * 528), dim3(256), 0, stream>>>(b2, adj, logits);
}